// Round 3
// baseline (75.396 us; speedup 1.0000x reference)
//
#include <hip/hip_runtime.h>
#include <math.h>

constexpr int Bb = 4, Cc = 64, Hh = 256, Ww = 256;

#define LOG2E 1.44269504088896340736f
#define LN2   0.69314718055994530942f

__device__ __forceinline__ unsigned int fenc(float f) {
  unsigned int u = __float_as_uint(f);
  return (u & 0x80000000u) ? ~u : (u | 0x80000000u);
}
__device__ __forceinline__ float fdec(unsigned int k) {
  return __uint_as_float((k & 0x80000000u) ? (k ^ 0x80000000u) : ~k);
}

// Grid: B*H blocks, block (64,8). Each block computes one output row (b,h);
// ty = channel group (8 channels each). Row min/max -> per-batch atomics.
// stats layout (uint): [0..3] = min keys per batch, [4..7] = max keys.
__global__ __launch_bounds__(512) void entropy_kernel(const float* __restrict__ x,
                                                      float* __restrict__ e,
                                                      unsigned int* __restrict__ stats) {
  const int b = blockIdx.x / Hh;
  const int h = blockIdx.x % Hh;
  const int tx = threadIdx.x;   // 0..63
  const int ty = threadIdx.y;   // 0..7
  const int w0 = tx * 4;

  float acc[4] = {0.f, 0.f, 0.f, 0.f};

  const size_t planeStride = (size_t)Hh * Ww;
  const float* xb = x + ((size_t)b * Cc + (size_t)ty * 8) * planeStride;

  for (int cc = 0; cc < 8; ++cc) {
    const float* plane = xb + (size_t)cc * planeStride;
    float va[3][4];
    float lft[3], rgt[3];
#pragma unroll
    for (int r = 0; r < 3; ++r) {
      const int hh2 = h + r - 1;
      float4 v;
      if (hh2 >= 0 && hh2 < Hh) {
        v = *reinterpret_cast<const float4*>(plane + (size_t)hh2 * Ww + w0);
      } else {
        v = make_float4(0.f, 0.f, 0.f, 0.f);
      }
      va[r][0] = v.x; va[r][1] = v.y; va[r][2] = v.z; va[r][3] = v.w;
      float l  = __shfl_up(v.w, 1, 64);
      float rr = __shfl_down(v.x, 1, 64);
      lft[r] = (tx == 0)  ? 0.f : l;
      rgt[r] = (tx == 63) ? 0.f : rr;
    }
#pragma unroll
    for (int i = 0; i < 4; ++i) {
      float vv[9];
#pragma unroll
      for (int r = 0; r < 3; ++r) {
        vv[r * 3 + 0] = (i == 0) ? lft[r] : va[r][i - 1];
        vv[r * 3 + 1] = va[r][i];
        vv[r * 3 + 2] = (i == 3) ? rgt[r] : va[r][i + 1];
      }
      // max-of-9 as a 3-3-3 tree (fuses to v_max3_f32).
      float a0 = fmaxf(fmaxf(vv[0], vv[1]), vv[2]);
      float a1 = fmaxf(fmaxf(vv[3], vv[4]), vv[5]);
      float a2 = fmaxf(fmaxf(vv[6], vv[7]), vv[8]);
      float m  = fmaxf(fmaxf(a0, a1), a2);
      const float mc = -m * LOG2E;
      float s = 0.f, ws = 0.f;
#pragma unroll
      for (int k = 0; k < 9; ++k) {
        float d = __builtin_fmaf(vv[k], LOG2E, mc);  // log2-domain shifted value
        float t = __builtin_amdgcn_exp2f(d);          // native v_exp_f32
        s += t;
        ws = __builtin_fmaf(t, d, ws);
      }
      // entropy = ln2 * (log2(s) - ws/s)
      acc[i] += LN2 * (__builtin_amdgcn_logf(s) - ws * __builtin_amdgcn_rcpf(s));
    }
  }

  // Reduce the 8 channel groups.
  __shared__ float red[8][4][64];
#pragma unroll
  for (int i = 0; i < 4; ++i) red[ty][i][tx] = acc[i];
  __syncthreads();
  if (ty == 0) {
    float4 o;
    float* op = &o.x;
    float mn = INFINITY, mx = -INFINITY;
#pragma unroll
    for (int i = 0; i < 4; ++i) {
      float v = 0.f;
#pragma unroll
      for (int t = 0; t < 8; ++t) v += red[t][i][tx];
      v *= (1.0f / Cc);
      op[i] = v;
      mn = fminf(mn, v);
      mx = fmaxf(mx, v);
    }
    *reinterpret_cast<float4*>(e + (size_t)blockIdx.x * Ww + w0) = o;

#pragma unroll
    for (int off = 32; off > 0; off >>= 1) {
      mn = fminf(mn, __shfl_down(mn, off, 64));
      mx = fmaxf(mx, __shfl_down(mx, off, 64));
    }
    if (tx == 0) {
      atomicMin(&stats[b], fenc(mn));
      atomicMax(&stats[4 + b], fenc(mx));
    }
  }
}

// In-place normalize d_out. 65536 threads, 4 elements each (float4).
__global__ __launch_bounds__(256) void norm_kernel(float* __restrict__ e,
                                                   const unsigned int* __restrict__ stats) {
  const int t = blockIdx.x * 256 + threadIdx.x;           // 0..65535
  const int b = t >> 14;                                  // (t*4) >> 16
  const float mn = fdec(stats[b]);
  const float mx = fdec(stats[4 + b]);
  const float inv = 1.0f / fmaxf(mx - mn, 1e-6f);
  float4 v = reinterpret_cast<float4*>(e)[t];
  v.x = (v.x - mn) * inv;
  v.y = (v.y - mn) * inv;
  v.z = (v.z - mn) * inv;
  v.w = (v.w - mn) * inv;
  reinterpret_cast<float4*>(e)[t] = v;
}

extern "C" void kernel_launch(void* const* d_in, const int* in_sizes, int n_in,
                              void* d_out, int out_size, void* d_ws, size_t ws_size,
                              hipStream_t stream) {
  const float* x = (const float*)d_in[0];
  float* out = (float*)d_out;                 // e, then normalized in place
  unsigned int* stats = (unsigned int*)d_ws;  // 8 uints

  // Init: min keys -> 0xFFFFFFFF, max keys -> 0.
  hipMemsetAsync(stats, 0xFF, 4 * sizeof(unsigned int), stream);
  hipMemsetAsync(stats + 4, 0x00, 4 * sizeof(unsigned int), stream);

  entropy_kernel<<<dim3(Bb * Hh), dim3(64, 8), 0, stream>>>(x, out, stats);
  norm_kernel<<<dim3((Bb * Hh * Ww / 4) / 256), dim3(256), 0, stream>>>(out, stats);
}